// Round 1
// baseline (680.541 us; speedup 1.0000x reference)
//
#include <hip/hip_runtime.h>
#include <math.h>

// Problem constants (match reference)
#define PP 6
#define MM 512
#define NN 4096
#define DD 1024
#define KSCALE 15.0f
#define BIGV 1e9f

// Tiling
#define BM 64
#define BN 128
#define BD 32
#define LDA 36          // BD + 4 pad: fragment reads land 2-way (free) on banks
#define LDC 129         // BN + 1 pad: phase-B reads 2-way with row = t&63 mapping
#define NSPLIT 16
#define CPB (NN / NSPLIT)   // 256 columns per block
#define NT (CPB / BN)       // 2 n-tiles per block
#define KI 6
#define KR 12
#define PARTW 20        // 6 intra + 12 inter + 2 sums

// branchless sorted-insert (ascending, drops largest). If v >= a[K-1] the
// chain is skipped (guard) or leaves the array unchanged (chain is idempotent
// for too-large v), both correct.
__device__ __forceinline__ void insert6(float (&a)[KI], float v) {
    if (v < a[KI - 1]) {
        float cur = v;
#pragma unroll
        for (int x = 0; x < KI; ++x) {
            float lo = fminf(a[x], cur);
            float hi = fmaxf(a[x], cur);
            a[x] = lo; cur = hi;
        }
    }
}
__device__ __forceinline__ void insert12(float (&a)[KR], float v) {
    if (v < a[KR - 1]) {
        float cur = v;
#pragma unroll
        for (int x = 0; x < KR; ++x) {
            float lo = fminf(a[x], cur);
            float hi = fmaxf(a[x], cur);
            a[x] = lo; cur = hi;
        }
    }
}

// Kernel 1: c2[p*N+n] = ||centers[p,n,:]||^2 ; also zeroes d_out (poisoned 0xAA)
__global__ __launch_bounds__(256)
void c2_kernel(const float* __restrict__ centers, float* __restrict__ c2,
               float* __restrict__ out) {
    if (blockIdx.x == 0 && threadIdx.x == 0) out[0] = 0.0f;
    int wid  = (blockIdx.x * 256 + threadIdx.x) >> 6;   // one wave per row
    int lane = threadIdx.x & 63;
    if (wid >= PP * NN) return;
    const float* base = centers + (size_t)wid * DD;
    float s = 0.0f;
#pragma unroll
    for (int k = 0; k < 4; ++k) {
        float4 v = *(const float4*)(base + lane * 4 + k * 256);
        s = fmaf(v.x, v.x, s); s = fmaf(v.y, v.y, s);
        s = fmaf(v.z, v.z, s); s = fmaf(v.w, v.w, s);
    }
#pragma unroll
    for (int off = 32; off > 0; off >>= 1) s += __shfl_down(s, off, 64);
    if (lane == 0) c2[wid] = s;
}

// Kernel 2: fused distance GEMM + online top-k + exp-sums.
// NOTE: f2[m] cancels in (-x + y) for both hinges and does not affect sort
// order within a row, so distances here are d' = c2[n] - 2*dot (no f2).
__global__ __launch_bounds__(256)
void dist_topk_kernel(const float* __restrict__ feature,
                      const int*   __restrict__ camid,
                      const float* __restrict__ centers,
                      const int*   __restrict__ cam,
                      const float* __restrict__ c2,
                      float*       __restrict__ partials) {
    const int ns = blockIdx.x;        // 0..NSPLIT-1
    const int mt = blockIdx.y;        // 0..M/BM-1
    const int p  = blockIdx.z;        // 0..P-1
    const int t  = threadIdx.x;
    const int tx = t & 15;
    const int ty = t >> 4;
    const int m0 = mt * BM;
    const int n0 = ns * CPB;

    // unioned LDS: staging (A 64x36 + B 128x36 = 6912 f) / dist (64x129 = 8256 f)
    // / merge (256x20 = 5120 f)
    __shared__ float smem[BM * LDC];          // 8256 floats = 33 KB
    __shared__ int   s_cam[BN];
    float* As = smem;                 // [BM][LDA]
    float* Bs = smem + BM * LDA;      // [BN][LDA]
    float* Ds = smem;                 // [BM][LDC]

    // phase-B identity: one row per lane index -> 2-way-free LDS reads
    const int prow = t & 63;
    const int pq   = t >> 6;          // column quarter
    const int my_cam = camid[m0 + prow];

    float ti[KI], tr[KR];
#pragma unroll
    for (int x = 0; x < KI; ++x) ti[x] = BIGV;
#pragma unroll
    for (int x = 0; x < KR; ++x) tr[x] = BIGV;
    float si = 0.0f, sr = 0.0f;

    const float* Abase  = feature + ((size_t)p * MM + m0) * DD;
    const float* Bbase0 = centers + (size_t)p * NN * DD;
    const float* c2p    = c2 + (size_t)p * NN;

    float acc[4][8];

    for (int nt = 0; nt < NT; ++nt) {
        const int nb = n0 + nt * BN;
        __syncthreads();              // prev dist tile fully consumed
        if (t < BN) s_cam[t] = cam[nb + t];
#pragma unroll
        for (int i = 0; i < 4; ++i)
#pragma unroll
            for (int j = 0; j < 8; ++j) acc[i][j] = 0.0f;

        const float* Bbase = Bbase0 + (size_t)nb * DD;

        for (int dk = 0; dk < DD; dk += BD) {
            if (dk) __syncthreads();  // prev chunk's compute done
            // stage A: 64x32 = 512 float4, 2/thread
#pragma unroll
            for (int i = 0; i < 2; ++i) {
                int f = t + i * 256;
                int r = f >> 3, k4 = (f & 7) * 4;
                float4 v = *(const float4*)(Abase + (size_t)r * DD + dk + k4);
                *(float4*)(As + r * LDA + k4) = v;
            }
            // stage B: 128x32 = 1024 float4, 4/thread
#pragma unroll
            for (int i = 0; i < 4; ++i) {
                int f = t + i * 256;
                int r = f >> 3, k4 = (f & 7) * 4;
                float4 v = *(const float4*)(Bbase + (size_t)r * DD + dk + k4);
                *(float4*)(Bs + r * LDA + k4) = v;
            }
            __syncthreads();
            // compute: rows i*16+ty, cols j*16+tx (interleaved -> 2-way banks)
#pragma unroll
            for (int kk = 0; kk < BD; kk += 4) {
                float4 a[4], b[8];
#pragma unroll
                for (int i = 0; i < 4; ++i)
                    a[i] = *(const float4*)(As + (i * 16 + ty) * LDA + kk);
#pragma unroll
                for (int j = 0; j < 8; ++j)
                    b[j] = *(const float4*)(Bs + (j * 16 + tx) * LDA + kk);
#pragma unroll
                for (int i = 0; i < 4; ++i)
#pragma unroll
                    for (int j = 0; j < 8; ++j) {
                        acc[i][j] = fmaf(a[i].x, b[j].x, acc[i][j]);
                        acc[i][j] = fmaf(a[i].y, b[j].y, acc[i][j]);
                        acc[i][j] = fmaf(a[i].z, b[j].z, acc[i][j]);
                        acc[i][j] = fmaf(a[i].w, b[j].w, acc[i][j]);
                    }
            }
        }
        // shifted distance d' = c2[n] - 2*dot
        float c2v[8];
#pragma unroll
        for (int j = 0; j < 8; ++j) c2v[j] = c2p[nb + j * 16 + tx];
        __syncthreads();              // all compute done; As/Bs free
#pragma unroll
        for (int i = 0; i < 4; ++i) {
            int r = i * 16 + ty;
#pragma unroll
            for (int j = 0; j < 8; ++j)
                Ds[r * LDC + j * 16 + tx] = c2v[j] - 2.0f * acc[i][j];
        }
        __syncthreads();
        // phase B: scan 32 columns of own row, update private top-k + sums
        for (int jj = 0; jj < 32; ++jj) {
            int c = pq * 32 + jj;
            float dd = Ds[prow * LDC + c];
            float e  = expf(-KSCALE * dd);
            if (s_cam[c] == my_cam) { si += e; insert6(ti, dd); }
            else                    { sr += e; insert12(tr, dd); }
        }
    }

    // intra-block merge: 4 threads per row -> 1 partial per row
    __syncthreads();
    float* msh = smem;                // [256][PARTW]
    {
        float* mine = msh + t * PARTW;
#pragma unroll
        for (int x = 0; x < KI; ++x) mine[x] = ti[x];
#pragma unroll
        for (int x = 0; x < KR; ++x) mine[KI + x] = tr[x];
        mine[18] = si; mine[19] = sr;
    }
    __syncthreads();
    if (t < 64) {
#pragma unroll
        for (int o = 1; o < 4; ++o) {
            const float* oth = msh + (t + o * 64) * PARTW;
#pragma unroll
            for (int x = 0; x < KI; ++x) insert6(ti, oth[x]);
#pragma unroll
            for (int x = 0; x < KR; ++x) insert12(tr, oth[KI + x]);
            si += oth[18]; sr += oth[19];
        }
        float* outp = partials +
            ((size_t)(p * MM + m0 + t) * NSPLIT + ns) * PARTW;
#pragma unroll
        for (int x = 0; x < KI; ++x) outp[x] = ti[x];
#pragma unroll
        for (int x = 0; x < KR; ++x) outp[KI + x] = tr[x];
        outp[18] = si; outp[19] = sr;
    }
}

// Kernel 3: merge NSPLIT partials per row, hinges, reduce, atomicAdd.
__global__ __launch_bounds__(256)
void finalize_kernel(const float* __restrict__ partials, float* __restrict__ out) {
    const int t   = threadIdx.x;
    const int row = blockIdx.x * 256 + t;   // 0..P*M-1
    float ti[KI], tr[KR];
#pragma unroll
    for (int x = 0; x < KI; ++x) ti[x] = BIGV;
#pragma unroll
    for (int x = 0; x < KR; ++x) tr[x] = BIGV;
    float si = 0.0f, sr = 0.0f;
    const float* base = partials + (size_t)row * NSPLIT * PARTW;
    for (int s = 0; s < NSPLIT; ++s) {
        const float* q = base + s * PARTW;
#pragma unroll
        for (int x = 0; x < KI; ++x) insert6(ti, q[x]);
#pragma unroll
        for (int x = 0; x < KR; ++x) insert12(tr, q[KI + x]);
        si += q[18]; sr += q[19];
    }
    float ei[KI], er[KR];
#pragma unroll
    for (int x = 0; x < KI; ++x) ei[x] = expf(-KSCALE * ti[x]);
#pragma unroll
    for (int x = 0; x < KR; ++x) er[x] = expf(-KSCALE * tr[x]);
    float x_intra = logf(ei[0] + ei[1] + ei[2] + ei[3]);
    float top6 = ei[0] + ei[1] + ei[2] + ei[3] + ei[4] + ei[5];
    float y_intra = logf(fmaxf(si - top6, 0.0f));   // exp(-15*BIG)=0 matches ref
    float x_inter = logf(er[0] + er[1] + er[2] + er[3] + er[4] + er[5] + er[6] + er[7]);
    float top12 = 0.0f;
#pragma unroll
    for (int x = 0; x < KR; ++x) top12 += er[x];
    float y_inter = logf(fmaxf(sr - top12, 0.0f));
    float h = fmaxf(y_intra - x_intra + 12.0f, 0.0f) +
              fmaxf(y_inter - x_inter + 5.0f, 0.0f);

    __shared__ float red[256];
    red[t] = h;
    __syncthreads();
#pragma unroll
    for (int s = 128; s > 0; s >>= 1) {
        if (t < s) red[t] += red[t + s];
        __syncthreads();
    }
    if (t == 0) atomicAdd(out, red[0] * (1.0f / (MM * PP)));
}

extern "C" void kernel_launch(void* const* d_in, const int* in_sizes, int n_in,
                              void* d_out, int out_size, void* d_ws, size_t ws_size,
                              hipStream_t stream) {
    const float* feature = (const float*)d_in[0];   // [P,M,D] fp32
    const int*   camid   = (const int*)  d_in[1];   // [M]
    const float* centers = (const float*)d_in[2];   // [P,N,D] fp32
    const int*   cam     = (const int*)  d_in[3];   // [N]
    float* out = (float*)d_out;

    // ws layout: c2 [P*N] floats | partials [P*M][NSPLIT][PARTW] floats (~4 MB)
    float* c2       = (float*)d_ws;
    float* partials = c2 + (size_t)PP * NN;

    c2_kernel<<<(PP * NN) / 4, 256, 0, stream>>>(centers, c2, out);
    dim3 grid(NSPLIT, MM / BM, PP);
    dist_topk_kernel<<<grid, 256, 0, stream>>>(feature, camid, centers, cam,
                                               c2, partials);
    finalize_kernel<<<(PP * MM) / 256, 256, 0, stream>>>(partials, out);
}

// Round 3
// 411.965 us; speedup vs baseline: 1.6519x; 1.6519x over previous
//
#include <hip/hip_runtime.h>
#include <math.h>

// Problem constants (match reference)
#define PP 6
#define MM 512
#define NN 4096
#define DD 1024
#define KSCALE 15.0f
#define BIGV 1e9f

// Tiling
#define BM 128
#define BN 128
#define BK 32
#define NCHUNK (DD / BK)   // 32
#define NSTRIP (NN / BN)   // 32 column strips -> grid.x
#define KI 6
#define KR 12
#define PARTW 20           // 6 intra + 12 inter + 2 sums

typedef __bf16 bf16x8 __attribute__((ext_vector_type(8)));
typedef float  f32x16 __attribute__((ext_vector_type(16)));

// branchless sorted-insert (ascending, drops largest)
__device__ __forceinline__ void insert6(float (&a)[KI], float v) {
    if (v < a[KI - 1]) {
        float cur = v;
#pragma unroll
        for (int x = 0; x < KI; ++x) {
            float lo = fminf(a[x], cur);
            float hi = fmaxf(a[x], cur);
            a[x] = lo; cur = hi;
        }
    }
}
__device__ __forceinline__ void insert12(float (&a)[KR], float v) {
    if (v < a[KR - 1]) {
        float cur = v;
#pragma unroll
        for (int x = 0; x < KR; ++x) {
            float lo = fminf(a[x], cur);
            float hi = fmaxf(a[x], cur);
            a[x] = lo; cur = hi;
        }
    }
}

// 8 fp32 -> hi/lo bf16x8 (split precision: x = hi + lo + O(2^-17 x))
__device__ __forceinline__ void cvt8(const float4& v0, const float4& v1,
                                     bf16x8& hi, bf16x8& lo) {
    float f[8] = {v0.x, v0.y, v0.z, v0.w, v1.x, v1.y, v1.z, v1.w};
#pragma unroll
    for (int i = 0; i < 8; ++i) {
        __bf16 h = (__bf16)f[i];
        hi[i] = h;
        lo[i] = (__bf16)(f[i] - (float)h);
    }
}

__device__ __forceinline__ float sq8(const float4& a, const float4& b) {
    float s = a.x * a.x;
    s = fmaf(a.y, a.y, s); s = fmaf(a.z, a.z, s); s = fmaf(a.w, a.w, s);
    s = fmaf(b.x, b.x, s); s = fmaf(b.y, b.y, s);
    s = fmaf(b.z, b.z, s); s = fmaf(b.w, b.w, s);
    return s;
}

// Fused: split-bf16 MFMA distance GEMM + in-block c2 + online top-k + exp-sums.
// d' = c2[n] - 2*dot  (f2[m] cancels in -x+y and preserves sort order).
__global__ __launch_bounds__(256, 2)
void dist_topk_kernel(const float* __restrict__ feature,
                      const int*   __restrict__ camid,
                      const float* __restrict__ centers,
                      const int*   __restrict__ cam,
                      float*       __restrict__ partials,
                      float*       __restrict__ out) {
    const int ns = blockIdx.x;        // 0..31 column strip
    const int mt = blockIdx.y;        // 0..3  row tile
    const int p  = blockIdx.z;        // 0..5
    const int t  = threadIdx.x;
    const int lane = t & 63, wid = t >> 6;
    const int wr = wid >> 1, wc = wid & 1;      // 2x2 wave grid, 64x64 per wave
    const int l31 = lane & 31, lh = lane >> 5;

    // Union LDS: staging = 2 buffers x 32KB {Ahi,Alo,Bhi,Blo planes [4][128][8]bf16}
    //            dist    = [128][129] fp32 (66048 B)   (after K-loop)
    //            merge   = [256][20] fp32              (after scan)
    __shared__ __align__(16) char smem[128 * 129 * 4];
    __shared__ float c2buf[128][4];
    __shared__ int   s_cam[128];

    if (blockIdx.x == 0 && blockIdx.y == 0 && blockIdx.z == 0 && t == 0)
        out[0] = 0.0f;
    if (t < BN) s_cam[t] = cam[ns * BN + t];
    const int my_cam = camid[mt * BM + (t & 127)];

    // staging mapping: idx = t: ks = t&3 (8-float k-subtile), row = t>>2 (+64)
    const int sk = t & 3;
    const int srow = t >> 2;
    const float* Abase = feature + ((size_t)p * MM + mt * BM) * DD;
    const float* Bbase = centers + ((size_t)p * NN + ns * BN) * DD;

    // LDS plane addressing (16B units): addr16 = ks*128 + (row ^ ks)  [XOR swizzle]
    const int wA0 = (sk * 128 + (srow ^ sk)) * 16;
    const int wA1 = (sk * 128 + ((srow + 64) ^ sk)) * 16;

    // fragment read offsets: ks = 2*step + lanehalf, row/col = w*64 + sub*32 + l31
    int aoff[2][2], boff[2][2];
#pragma unroll
    for (int s = 0; s < 2; ++s) {
        int ks = 2 * s + lh;
#pragma unroll
        for (int q = 0; q < 2; ++q) {
            int row = wr * 64 + q * 32 + l31;
            int col = wc * 64 + q * 32 + l31;
            aoff[q][s] = (ks * 128 + (row ^ ks)) * 16;
            boff[q][s] = (ks * 128 + (col ^ ks)) * 16;
        }
    }

    f32x16 acc[2][2];
#pragma unroll
    for (int i = 0; i < 2; ++i)
#pragma unroll
        for (int j = 0; j < 2; ++j)
#pragma unroll
            for (int r = 0; r < 16; ++r) acc[i][j][r] = 0.0f;

    float c2p0 = 0.0f, c2p1 = 0.0f;

    const float4* gA0 = (const float4*)(Abase + (size_t)srow * DD) + sk * 2;
    const float4* gA1 = (const float4*)(Abase + (size_t)(srow + 64) * DD) + sk * 2;
    const float4* gB0 = (const float4*)(Bbase + (size_t)srow * DD) + sk * 2;
    const float4* gB1 = (const float4*)(Bbase + (size_t)(srow + 64) * DD) + sk * 2;

    auto stage_write = [&](int buf,
                           const float4& a00, const float4& a01,
                           const float4& a10, const float4& a11,
                           const float4& b00, const float4& b01,
                           const float4& b10, const float4& b11) {
        char* base = smem + buf * 32768;
        bf16x8 hi, lo;
        cvt8(a00, a01, hi, lo);
        *(bf16x8*)(base + 0     + wA0) = hi;
        *(bf16x8*)(base + 8192  + wA0) = lo;
        cvt8(a10, a11, hi, lo);
        *(bf16x8*)(base + 0     + wA1) = hi;
        *(bf16x8*)(base + 8192  + wA1) = lo;
        cvt8(b00, b01, hi, lo);
        *(bf16x8*)(base + 16384 + wA0) = hi;
        *(bf16x8*)(base + 24576 + wA0) = lo;
        cvt8(b10, b11, hi, lo);
        *(bf16x8*)(base + 16384 + wA1) = hi;
        *(bf16x8*)(base + 24576 + wA1) = lo;
        c2p0 += sq8(b00, b01);
        c2p1 += sq8(b10, b11);
    };

    // prologue: stage chunk 0 into buffer 0
    {
        float4 a00 = gA0[0], a01 = gA0[1], a10 = gA1[0], a11 = gA1[1];
        float4 b00 = gB0[0], b01 = gB0[1], b10 = gB1[0], b11 = gB1[1];
        stage_write(0, a00, a01, a10, a11, b00, b01, b10, b11);
    }
    __syncthreads();

    for (int c = 0; c < NCHUNK; ++c) {
        const int cur = c & 1;
        float4 na00, na01, na10, na11, nb00, nb01, nb10, nb11;
        if (c + 1 < NCHUNK) {           // issue prefetch loads before MFMAs
            const int o = (c + 1) * 8;
            na00 = gA0[o]; na01 = gA0[o + 1];
            na10 = gA1[o]; na11 = gA1[o + 1];
            nb00 = gB0[o]; nb01 = gB0[o + 1];
            nb10 = gB1[o]; nb11 = gB1[o + 1];
        }
        const char* bb = smem + cur * 32768;
#pragma unroll
        for (int s = 0; s < 2; ++s) {
            bf16x8 ahi[2], alo[2], bhi[2], blo[2];
#pragma unroll
            for (int q = 0; q < 2; ++q) {
                ahi[q] = *(const bf16x8*)(bb + 0     + aoff[q][s]);
                alo[q] = *(const bf16x8*)(bb + 8192  + aoff[q][s]);
                bhi[q] = *(const bf16x8*)(bb + 16384 + boff[q][s]);
                blo[q] = *(const bf16x8*)(bb + 24576 + boff[q][s]);
            }
#pragma unroll
            for (int mi = 0; mi < 2; ++mi)
#pragma unroll
                for (int nj = 0; nj < 2; ++nj) {
                    acc[mi][nj] = __builtin_amdgcn_mfma_f32_32x32x16_bf16(
                        ahi[mi], bhi[nj], acc[mi][nj], 0, 0, 0);
                    acc[mi][nj] = __builtin_amdgcn_mfma_f32_32x32x16_bf16(
                        ahi[mi], blo[nj], acc[mi][nj], 0, 0, 0);
                    acc[mi][nj] = __builtin_amdgcn_mfma_f32_32x32x16_bf16(
                        alo[mi], bhi[nj], acc[mi][nj], 0, 0, 0);
                }
        }
        if (c + 1 < NCHUNK)
            stage_write(cur ^ 1, na00, na01, na10, na11, nb00, nb01, nb10, nb11);
        __syncthreads();
    }

    // c2 totals (fp32, from original values accumulated during staging)
    c2buf[srow][sk]      = c2p0;
    c2buf[srow + 64][sk] = c2p1;
    __syncthreads();

    float* distS = (float*)smem;
    float c2v[2];
#pragma unroll
    for (int nj = 0; nj < 2; ++nj) {
        int C = wc * 64 + nj * 32 + l31;
        float4 q = *(const float4*)&c2buf[C][0];
        c2v[nj] = (q.x + q.y) + (q.z + q.w);
    }
    // write dist tile: C/D layout col = lane&31, row = (r&3)+8*(r>>2)+4*(lane>>5)
#pragma unroll
    for (int mi = 0; mi < 2; ++mi)
#pragma unroll
        for (int nj = 0; nj < 2; ++nj) {
            int C = wc * 64 + nj * 32 + l31;
#pragma unroll
            for (int r = 0; r < 16; ++r) {
                int R = wr * 64 + mi * 32 + (r & 3) + 8 * (r >> 2) + 4 * lh;
                distS[R * 129 + C] = c2v[nj] - 2.0f * acc[mi][nj][r];
            }
        }
    __syncthreads();

    // phase B: 2 threads per row scan 64 cols each
    const int prow = t & 127, half = t >> 7;
    float ti[KI], tr[KR];
#pragma unroll
    for (int x = 0; x < KI; ++x) ti[x] = BIGV;
#pragma unroll
    for (int x = 0; x < KR; ++x) tr[x] = BIGV;
    float si = 0.0f, sr = 0.0f;
    const float* drow = distS + prow * 129 + half * 64;
    const int*   crow = s_cam + half * 64;
    for (int jj = 0; jj < 64; ++jj) {
        float dd = drow[jj];
        float e  = __expf(-KSCALE * dd);
        if (crow[jj] == my_cam) { si += e; insert6(ti, dd); }
        else                    { sr += e; insert12(tr, dd); }
    }
    __syncthreads();                  // dist fully consumed

    // merge the 2 partials per row, write to global
    float* msh = (float*)smem;        // [256][PARTW]
    {
        float* mine = msh + t * PARTW;
#pragma unroll
        for (int x = 0; x < KI; ++x) mine[x] = ti[x];
#pragma unroll
        for (int x = 0; x < KR; ++x) mine[KI + x] = tr[x];
        mine[18] = si; mine[19] = sr;
    }
    __syncthreads();
    if (t < 128) {
        const float* oth = msh + (t + 128) * PARTW;
#pragma unroll
        for (int x = 0; x < KI; ++x) insert6(ti, oth[x]);
#pragma unroll
        for (int x = 0; x < KR; ++x) insert12(tr, oth[KI + x]);
        si += oth[18]; sr += oth[19];
        float* outp = partials +
            ((size_t)(p * MM + mt * BM + t) * NSTRIP + ns) * PARTW;
#pragma unroll
        for (int x = 0; x < KI; ++x) outp[x] = ti[x];
#pragma unroll
        for (int x = 0; x < KR; ++x) outp[KI + x] = tr[x];
        outp[18] = si; outp[19] = sr;
    }
}

// merge NSTRIP partials per row, hinges, reduce, atomicAdd
__global__ __launch_bounds__(256)
void finalize_kernel(const float* __restrict__ partials, float* __restrict__ out) {
    const int t   = threadIdx.x;
    const int row = blockIdx.x * 256 + t;   // 0..P*M-1
    float ti[KI], tr[KR];
#pragma unroll
    for (int x = 0; x < KI; ++x) ti[x] = BIGV;
#pragma unroll
    for (int x = 0; x < KR; ++x) tr[x] = BIGV;
    float si = 0.0f, sr = 0.0f;
    const float* base = partials + (size_t)row * NSTRIP * PARTW;
    for (int s = 0; s < NSTRIP; ++s) {
        const float* q = base + s * PARTW;
#pragma unroll
        for (int x = 0; x < KI; ++x) insert6(ti, q[x]);
#pragma unroll
        for (int x = 0; x < KR; ++x) insert12(tr, q[KI + x]);
        si += q[18]; sr += q[19];
    }
    float ei[KI], er[KR];
#pragma unroll
    for (int x = 0; x < KI; ++x) ei[x] = __expf(-KSCALE * ti[x]);
#pragma unroll
    for (int x = 0; x < KR; ++x) er[x] = __expf(-KSCALE * tr[x]);
    float x_intra = logf(ei[0] + ei[1] + ei[2] + ei[3]);
    float top6 = ei[0] + ei[1] + ei[2] + ei[3] + ei[4] + ei[5];
    float y_intra = logf(fmaxf(si - top6, 0.0f));
    float x_inter = logf(er[0] + er[1] + er[2] + er[3] +
                         er[4] + er[5] + er[6] + er[7]);
    float top12 = 0.0f;
#pragma unroll
    for (int x = 0; x < KR; ++x) top12 += er[x];
    float y_inter = logf(fmaxf(sr - top12, 0.0f));
    float h = fmaxf(y_intra - x_intra + 12.0f, 0.0f) +
              fmaxf(y_inter - x_inter + 5.0f, 0.0f);

    __shared__ float red[256];
    red[t] = h;
    __syncthreads();
#pragma unroll
    for (int s = 128; s > 0; s >>= 1) {
        if (t < s) red[t] += red[t + s];
        __syncthreads();
    }
    if (t == 0) atomicAdd(out, red[0] * (1.0f / (MM * PP)));
}

extern "C" void kernel_launch(void* const* d_in, const int* in_sizes, int n_in,
                              void* d_out, int out_size, void* d_ws, size_t ws_size,
                              hipStream_t stream) {
    const float* feature = (const float*)d_in[0];   // [P,M,D] fp32
    const int*   camid   = (const int*)  d_in[1];   // [M]
    const float* centers = (const float*)d_in[2];   // [P,N,D] fp32
    const int*   cam     = (const int*)  d_in[3];   // [N]
    float* out = (float*)d_out;

    // ws: partials [P*M][NSTRIP][PARTW] floats (~7.9 MB)
    float* partials = (float*)d_ws;

    dim3 grid(NSTRIP, MM / BM, PP);
    dist_topk_kernel<<<grid, 256, 0, stream>>>(feature, camid, centers, cam,
                                               partials, out);
    finalize_kernel<<<(PP * MM) / 256, 256, 0, stream>>>(partials, out);
}

// Round 5
// 358.344 us; speedup vs baseline: 1.8991x; 1.1496x over previous
//
#include <hip/hip_runtime.h>
#include <math.h>

// Problem constants (match reference)
#define PP 6
#define MM 512
#define NN 4096
#define DD 1024
#define KSCALE 15.0f
#define BIGV 1e9f

// Tiling
#define BM 128
#define BN 128
#define BK 16
#define NCHUNK (DD / BK)    // 64
#define NSTRIP (NN / BN)    // 32
#define KI 6
#define KR 12
#define PARTW 20            // 6 intra + 12 inter + 2 sums
#define LDSB 16384          // bytes per staging buffer (2 planes x 2 ks x 256 rows x 16B)

typedef __bf16 bf16x8 __attribute__((ext_vector_type(8)));
typedef float  f32x16 __attribute__((ext_vector_type(16)));

// branchless sorted-insert (ascending, drops largest)
__device__ __forceinline__ void insert6(float (&a)[KI], float v) {
    if (v < a[KI - 1]) {
        float cur = v;
#pragma unroll
        for (int x = 0; x < KI; ++x) {
            float lo = fminf(a[x], cur);
            float hi = fmaxf(a[x], cur);
            a[x] = lo; cur = hi;
        }
    }
}
__device__ __forceinline__ void insert12(float (&a)[KR], float v) {
    if (v < a[KR - 1]) {
        float cur = v;
#pragma unroll
        for (int x = 0; x < KR; ++x) {
            float lo = fminf(a[x], cur);
            float hi = fmaxf(a[x], cur);
            a[x] = lo; cur = hi;
        }
    }
}

// ---------- decompose kernels: fp32 -> hi/lo bf16 planes (+ c2 for centers) ----

__global__ __launch_bounds__(256)
void decomp_feat(const float* __restrict__ f,
                 __bf16* __restrict__ hi, __bf16* __restrict__ lo) {
    size_t base = ((size_t)blockIdx.x * 256 + threadIdx.x) * 8;
    float4 v0 = *(const float4*)(f + base);
    float4 v1 = *(const float4*)(f + base + 4);
    float fv[8] = {v0.x, v0.y, v0.z, v0.w, v1.x, v1.y, v1.z, v1.w};
    bf16x8 h, l;
#pragma unroll
    for (int i = 0; i < 8; ++i) {
        __bf16 hh = (__bf16)fv[i];
        h[i] = hh;
        l[i] = (__bf16)(fv[i] - (float)hh);
    }
    *(bf16x8*)(hi + base) = h;
    *(bf16x8*)(lo + base) = l;
}

__global__ __launch_bounds__(256)
void decomp_cent(const float* __restrict__ cz,
                 __bf16* __restrict__ hi, __bf16* __restrict__ lo,
                 float* __restrict__ c2, float* __restrict__ out) {
    if (blockIdx.x == 0 && threadIdx.x == 0) out[0] = 0.0f;   // un-poison output
    const int row  = blockIdx.x * 4 + (threadIdx.x >> 6);     // one wave per row
    const int lane = threadIdx.x & 63;
    const size_t eb = (size_t)row * DD + lane * 16;
    float s = 0.0f;
#pragma unroll
    for (int g = 0; g < 2; ++g) {
        float4 v0 = *(const float4*)(cz + eb + g * 8);
        float4 v1 = *(const float4*)(cz + eb + g * 8 + 4);
        float fv[8] = {v0.x, v0.y, v0.z, v0.w, v1.x, v1.y, v1.z, v1.w};
        bf16x8 h, l;
#pragma unroll
        for (int i = 0; i < 8; ++i) {
            s = fmaf(fv[i], fv[i], s);
            __bf16 hh = (__bf16)fv[i];
            h[i] = hh;
            l[i] = (__bf16)(fv[i] - (float)hh);
        }
        *(bf16x8*)(hi + eb + g * 8) = h;
        *(bf16x8*)(lo + eb + g * 8) = l;
    }
#pragma unroll
    for (int off = 32; off > 0; off >>= 1) s += __shfl_down(s, off, 64);
    if (lane == 0) c2[row] = s;
}

// ---------- fused distance GEMM (split-bf16 MFMA) + band-scan top-k ----------
// d' = c2[n] - 2*dot  (f2[m] cancels in -x+y and preserves sort order).

__global__ __launch_bounds__(256, 3)
void dist_topk_kernel(const __bf16* __restrict__ Fhi, const __bf16* __restrict__ Flo,
                      const __bf16* __restrict__ Chi, const __bf16* __restrict__ Clo,
                      const float* __restrict__ c2g,
                      const int* __restrict__ camid, const int* __restrict__ cam,
                      float* __restrict__ partials) {
    const int ns = blockIdx.x;          // 0..31 column strip
    const int mt = blockIdx.y;          // 0..3  row tile
    const int p  = blockIdx.z;          // 0..5
    const int t  = threadIdx.x;
    const int lane = t & 63, w = t >> 6;
    const int wr = w >> 1, wc = w & 1;  // 2x2 wave grid, 64x64 per wave
    const int l31 = lane & 31, lh = lane >> 5;

    // staging: 2 buffers x 16KB, LINEAR layout, unit16B = plane*512 + ks*256 + row
    //   rows 0..127 = A (feature), 128..255 = B (centers); plane 0=hi, 1=lo
    // band buffer: [128 rows][33] f32, separate region
    __shared__ __align__(16) char smem[2 * LDSB + 128 * 33 * 4];
    __shared__ int s_cam[BN];
    float* bandS = (float*)(smem + 2 * LDSB);

    if (t < BN) s_cam[t] = cam[ns * BN + t];

    // per-thread staging sources: 4 global_load_lds issues per chunk
    // r_idx = w*4+i: plane=r_idx>>3, ks=(r_idx>>2)&1, row=(r_idx&3)*64+lane
    const char* srcp[4];
    int ldsoff[4];
#pragma unroll
    for (int i = 0; i < 4; ++i) {
        const int r_idx = w * 4 + i;
        const int plane = r_idx >> 3;
        const int ks    = (r_idx >> 2) & 1;
        const int row   = (r_idx & 3) * 64 + lane;
        const __bf16* basep;
        size_t gr;
        if (row < BM) { basep = plane ? Flo : Fhi; gr = (size_t)(p * MM + mt * BM + row) * DD; }
        else          { basep = plane ? Clo : Chi; gr = (size_t)(p * NN + ns * BN + row - BM) * DD; }
        srcp[i]   = (const char*)(basep + gr + ks * 8);
        ldsoff[i] = r_idx * 1024;       // wave-uniform LDS base; HW adds lane*16
    }

    // fragment read byte offsets (within a buffer): unit*16
    int aU[2], bU[2];
#pragma unroll
    for (int x = 0; x < 2; ++x) {
        aU[x] = (lh * 256 + wr * 64 + x * 32 + l31) * 16;
        bU[x] = (lh * 256 + 128 + wc * 64 + x * 32 + l31) * 16;
    }

    f32x16 acc[2][2];
#pragma unroll
    for (int i = 0; i < 2; ++i)
#pragma unroll
        for (int j = 0; j < 2; ++j)
#pragma unroll
            for (int r = 0; r < 16; ++r) acc[i][j][r] = 0.0f;

    auto stage = [&](int buf, int c) {
#pragma unroll
        for (int i = 0; i < 4; ++i)
            __builtin_amdgcn_global_load_lds(
                (const __attribute__((address_space(1))) void*)(srcp[i] + (size_t)c * 32),
                (__attribute__((address_space(3))) void*)(smem + buf * LDSB + ldsoff[i]),
                16, 0, 0);
    };

    stage(0, 0);
    __syncthreads();

    for (int c = 0; c < NCHUNK; ++c) {
        const int cur = c & 1;
        if (c + 1 < NCHUNK) stage(cur ^ 1, c + 1);   // prefetch overlaps compute
        const char* bb = smem + cur * LDSB;
        bf16x8 ah[2], al[2], bh[2], bl[2];
#pragma unroll
        for (int x = 0; x < 2; ++x) {
            ah[x] = *(const bf16x8*)(bb + aU[x]);
            al[x] = *(const bf16x8*)(bb + 8192 + aU[x]);
            bh[x] = *(const bf16x8*)(bb + bU[x]);
            bl[x] = *(const bf16x8*)(bb + 8192 + bU[x]);
        }
#pragma unroll
        for (int mi = 0; mi < 2; ++mi)
#pragma unroll
            for (int nj = 0; nj < 2; ++nj) {
                acc[mi][nj] = __builtin_amdgcn_mfma_f32_32x32x16_bf16(
                    ah[mi], bh[nj], acc[mi][nj], 0, 0, 0);
                acc[mi][nj] = __builtin_amdgcn_mfma_f32_32x32x16_bf16(
                    ah[mi], bl[nj], acc[mi][nj], 0, 0, 0);
                acc[mi][nj] = __builtin_amdgcn_mfma_f32_32x32x16_bf16(
                    al[mi], bh[nj], acc[mi][nj], 0, 0, 0);
            }
        __syncthreads();
    }

    // epilogue: c2 per lane-column
    float c2v[2];
#pragma unroll
    for (int nj = 0; nj < 2; ++nj)
        c2v[nj] = c2g[p * NN + ns * BN + wc * 64 + nj * 32 + l31];

    const int myrow = t >> 1, half = t & 1;   // 2 threads per row, fixed across bands
    const int my_cam = camid[mt * BM + myrow];
    float ti[KI], tr[KR];
#pragma unroll
    for (int x = 0; x < KI; ++x) ti[x] = BIGV;
#pragma unroll
    for (int x = 0; x < KR; ++x) tr[x] = BIGV;
    float si = 0.0f, sr = 0.0f;

    // 4 column-bands of 32 cols; band b written by waves with wc == b>>1 (nj = b&1)
#pragma unroll
    for (int b = 0; b < 4; ++b) {
        __syncthreads();                 // previous band fully consumed
        if (wc == (b >> 1)) {
            const int nj = b & 1;
#pragma unroll
            for (int mi = 0; mi < 2; ++mi)
#pragma unroll
                for (int r = 0; r < 16; ++r) {
                    // C/D layout: col = lane&31, row = (r&3)+8*(r>>2)+4*(lane>>5)
                    int R = wr * 64 + mi * 32 + (r & 3) + 8 * (r >> 2) + 4 * lh;
                    bandS[R * 33 + l31] = c2v[nj] - 2.0f * acc[mi][nj][r];
                }
        }
        __syncthreads();
        const float* drow = bandS + myrow * 33 + half * 16;
        const int*   crow = s_cam + b * 32 + half * 16;
#pragma unroll
        for (int j = 0; j < 16; ++j) {
            float dd = drow[j];
            float e  = __expf(-KSCALE * dd);
            if (crow[j] == my_cam) { si += e; insert6(ti, dd); }
            else                   { sr += e; insert12(tr, dd); }
        }
    }

    // merge the 2 threads per row via lane^1 shuffle (snapshot first, then insert)
    float oti[KI], otr[KR];
#pragma unroll
    for (int x = 0; x < KI; ++x) oti[x] = __shfl_xor(ti[x], 1, 64);
#pragma unroll
    for (int x = 0; x < KR; ++x) otr[x] = __shfl_xor(tr[x], 1, 64);
    float osi = __shfl_xor(si, 1, 64), osr = __shfl_xor(sr, 1, 64);
#pragma unroll
    for (int x = 0; x < KI; ++x) insert6(ti, oti[x]);
#pragma unroll
    for (int x = 0; x < KR; ++x) insert12(tr, otr[x]);
    si += osi; sr += osr;

    if (!half) {
        float* outp = partials +
            ((size_t)(p * MM + mt * BM + myrow) * NSTRIP + ns) * PARTW;
#pragma unroll
        for (int x = 0; x < KI; ++x) outp[x] = ti[x];
#pragma unroll
        for (int x = 0; x < KR; ++x) outp[KI + x] = tr[x];
        outp[18] = si; outp[19] = sr;
    }
}

// ---------- finalize: one wave per row, lane=strip, shuffle-butterfly merge ----

__global__ __launch_bounds__(256)
void finalize_kernel(const float* __restrict__ partials, float* __restrict__ out) {
    const int t = threadIdx.x, lane = t & 63, w = t >> 6;
    const int row = blockIdx.x * 4 + w;        // 0..P*M-1
    const int strip = lane & 31;               // lanes 32-63 mirror (harmless)
    const float* q = partials + ((size_t)row * NSTRIP + strip) * PARTW;
    float ti[KI], tr[KR];
#pragma unroll
    for (int x = 0; x < KI; ++x) ti[x] = q[x];
#pragma unroll
    for (int x = 0; x < KR; ++x) tr[x] = q[KI + x];
    float si = q[18], sr = q[19];

#pragma unroll
    for (int s = 1; s < 32; s <<= 1) {
        float oti[KI], otr[KR];
#pragma unroll
        for (int x = 0; x < KI; ++x) oti[x] = __shfl_xor(ti[x], s, 64);
#pragma unroll
        for (int x = 0; x < KR; ++x) otr[x] = __shfl_xor(tr[x], s, 64);
        float osi = __shfl_xor(si, s, 64), osr = __shfl_xor(sr, s, 64);
#pragma unroll
        for (int x = 0; x < KI; ++x) insert6(ti, oti[x]);
#pragma unroll
        for (int x = 0; x < KR; ++x) insert12(tr, otr[x]);
        si += osi; sr += osr;
    }

    if (lane == 0) {
        float ei[KI], er[KR];
#pragma unroll
        for (int x = 0; x < KI; ++x) ei[x] = __expf(-KSCALE * ti[x]);
#pragma unroll
        for (int x = 0; x < KR; ++x) er[x] = __expf(-KSCALE * tr[x]);
        float x_intra = logf(ei[0] + ei[1] + ei[2] + ei[3]);
        float top6 = ei[0] + ei[1] + ei[2] + ei[3] + ei[4] + ei[5];
        float y_intra = logf(fmaxf(si - top6, 0.0f));   // exp(-15*BIG)=0 matches ref
        float x_inter = logf(er[0] + er[1] + er[2] + er[3] +
                             er[4] + er[5] + er[6] + er[7]);
        float top12 = 0.0f;
#pragma unroll
        for (int x = 0; x < KR; ++x) top12 += er[x];
        float y_inter = logf(fmaxf(sr - top12, 0.0f));
        float h = fmaxf(y_intra - x_intra + 12.0f, 0.0f) +
                  fmaxf(y_inter - x_inter + 5.0f, 0.0f);
        atomicAdd(out, h * (1.0f / (MM * PP)));
    }
}

extern "C" void kernel_launch(void* const* d_in, const int* in_sizes, int n_in,
                              void* d_out, int out_size, void* d_ws, size_t ws_size,
                              hipStream_t stream) {
    const float* feature = (const float*)d_in[0];   // [P,M,D] fp32
    const int*   camid   = (const int*)  d_in[1];   // [M]
    const float* centers = (const float*)d_in[2];   // [P,N,D] fp32
    const int*   cam     = (const int*)  d_in[3];   // [N]
    float* out = (float*)d_out;

    // ws layout (bytes):
    //   Chi 50,331,648 | Clo 50,331,648 | Fhi 6,291,456 | Flo 6,291,456
    //   c2 98,304 | partials 7,864,320   -> total 121,208,832
    char* ws = (char*)d_ws;
    __bf16* Chi = (__bf16*)(ws);
    __bf16* Clo = (__bf16*)(ws + 50331648);
    __bf16* Fhi = (__bf16*)(ws + 100663296);
    __bf16* Flo = (__bf16*)(ws + 106954752);
    float*  c2  = (float*) (ws + 113246208);
    float*  partials = (float*)(ws + 113344512);

    decomp_feat<<<(PP * MM * DD / 8) / 256, 256, 0, stream>>>(feature, Fhi, Flo);
    decomp_cent<<<(PP * NN) / 4, 256, 0, stream>>>(centers, Chi, Clo, c2, out);
    dim3 grid(NSTRIP, MM / BM, PP);
    dist_topk_kernel<<<grid, 256, 0, stream>>>(Fhi, Flo, Chi, Clo, c2,
                                               camid, cam, partials);
    finalize_kernel<<<(PP * MM) / 4, 256, 0, stream>>>(partials, out);
}